// Round 14
// baseline (3240.334 us; speedup 1.0000x reference)
//
#include <hip/hip_runtime.h>

#define NT 512
#define ND 256
#define NH 1024
#define NB 64
// R14 = R11 protocol (proven: per-step flag rows, sc0 sc1 everywhere, 2 barriers)
// + latency hiding only:
//  - x_{t+1} prefetched into regs during step t (asm, retired by tail vmcnt(0))
//  - flag-row load issued at step tail, checked next step after x-part
//  - counted vmcnt(8) so outs4+xpref4 fly through the h-MFMA section
// No scope changes, no new race surface (R13's sc0-only scope deadlocked: sc0
// loads can hit stale lines — cross-CU handoff needs the sc1/LLC path).

typedef float f32x4 __attribute__((ext_vector_type(4)));
typedef short bf16x8 __attribute__((ext_vector_type(8)));

__device__ __forceinline__ unsigned short f2bf(float f) {     // RNE
  unsigned u = __builtin_bit_cast(unsigned, f);
  u += 0x7fffu + ((u >> 16) & 1u);
  return (unsigned short)(u >> 16);
}
__device__ __forceinline__ float bflo(unsigned u) {
  return __builtin_bit_cast(float, u << 16);
}
__device__ __forceinline__ float bfhi(unsigned u) {
  return __builtin_bit_cast(float, u & 0xffff0000u);
}
__device__ __forceinline__ bf16x8 pack8(float4 a, float4 b) {
  bf16x8 r;
  r[0] = (short)f2bf(a.x); r[1] = (short)f2bf(a.y);
  r[2] = (short)f2bf(a.z); r[3] = (short)f2bf(a.w);
  r[4] = (short)f2bf(b.x); r[5] = (short)f2bf(b.y);
  r[6] = (short)f2bf(b.z); r[7] = (short)f2bf(b.w);
  return r;
}

__global__ void __launch_bounds__(256, 1)
rnn_step_kernel(const float* __restrict__ x,
                const float* __restrict__ Wx_w,
                const float* __restrict__ Wx_b,
                const float* __restrict__ Wh_w,
                const float* __restrict__ Ws_w,
                const float* __restrict__ Ws_b,
                const float* __restrict__ Us_w,
                float* __restrict__ out,
                unsigned short* __restrict__ hbuf,   // bf16 [2][NB][NH]
                unsigned int* __restrict__ flags)    // [4][NT][64]
{
  const int tid = (int)threadIdx.x;
  const int w   = tid >> 6;        // wave
  const int l   = tid & 63;        // lane
  const int bm  = l & 15;          // mfma row/col index for A/B frags
  const int lg  = l >> 4;          // lane group
  const int sl  = (int)blockIdx.x & 63;
  const int bg  = (int)blockIdx.x >> 6;
  const int r_base = sl * 16;
  const int b_base = bg * 16;
  const int ro = tid & 15;         // epilogue: consecutive lanes -> rows
  const int bo = tid >> 4;
  const int rg = r_base + ro;
  const int b_glob = b_base + bo;

  __shared__ unsigned short us_sh[1024];   // bf16 Us (broadcast reads)
  __shared__ float cpart[4][4][72];        // per-wave C partials, padded
  __shared__ float gpart[4][16];           // per-wave gate partials

  // ---- one-time: Us -> bf16 LDS ----
  {
    const float4 uv = *(const float4*)(Us_w + tid*4);
    us_sh[tid*4+0] = f2bf(uv.x); us_sh[tid*4+1] = f2bf(uv.y);
    us_sh[tid*4+2] = f2bf(uv.z); us_sh[tid*4+3] = f2bf(uv.w);
  }

  // ---- A-fragments in registers (bf16), held all 512 steps ----
  // A layout (m89): row = l&15, k = ktile + (l>>4)*8 + j
  bf16x8 whf[8];   // wave w: h-K slice [w*256,+256) -> 8 mfma
  bf16x8 wxf[2];   // wave w: x-K slice [w*64,+64)   -> 2 mfma
  float4 wsf[4];   // Ws f32 slice for gate-x (exact f32 math)
  {
    const int ar = r_base + bm;
    #pragma unroll
    for (int m = 0; m < 8; ++m) {
      const int k0 = w*256 + m*32 + lg*8;
      const float4 f0 = *(const float4*)(Wh_w + (size_t)ar*NH + k0);
      const float4 f1 = *(const float4*)(Wh_w + (size_t)ar*NH + k0 + 4);
      whf[m] = pack8(f0, f1);
    }
    #pragma unroll
    for (int m = 0; m < 2; ++m) {
      const int k0 = w*64 + m*32 + lg*8;
      const float4 f0 = *(const float4*)(Wx_w + (size_t)ar*ND + k0);
      const float4 f1 = *(const float4*)(Wx_w + (size_t)ar*ND + k0 + 4);
      wxf[m] = pack8(f0, f1);
      wsf[m*2]   = *(const float4*)(Ws_w + k0);
      wsf[m*2+1] = *(const float4*)(Ws_w + k0 + 4);
    }
  }
  const float wxb_r = Wx_b[rg];
  const float whd_r = Wh_w[(size_t)rg*NH + rg];
  const float usr_r = Us_w[rg];
  const float wsb   = Ws_b[0];

  float* const hs_o = out + (size_t)NB*NT;
  float* const g_o  = hs_o + (size_t)NB*NT*NH;
  float* const l_o  = g_o  + (size_t)NB*NT*NH;
  float* const rd_o = l_o  + (size_t)NB*NT*NH;

  __syncthreads();

  float myh = 0.f;
  float p_sg = 0.f, p_htld = 0.f, p_hp = 0.f;
  unsigned flagv = 0;            // early-issued flag row value (loop-carried)
  float4 xq0, xq1, xq2, xq3;     // x for current step (loop-carried, retired)

  // ---- prologue: x_0 into registers ----
  {
    const float* xr = x + ((size_t)(b_base + bm)*NT + 0)*ND + w*64 + lg*8;
    asm volatile(
      "global_load_dwordx4 %0, %4, off\n\t"
      "global_load_dwordx4 %1, %4, off offset:16\n\t"
      "global_load_dwordx4 %2, %4, off offset:128\n\t"
      "global_load_dwordx4 %3, %4, off offset:144\n\t"
      "s_waitcnt vmcnt(0)"
      : "=&v"(xq0), "=&v"(xq1), "=&v"(xq2), "=&v"(xq3)
      : "v"(xr) : "memory");
    __builtin_amdgcn_sched_barrier(0);
  }

  for (int t = 0; t < NT; ++t) {
    // ---- 1. x-part from prefetched regs: 2 mfma + gate-x (f32) ----
    f32x4 acc = {0.f, 0.f, 0.f, 0.f};
    float ga = wsf[0].x*xq0.x + wsf[0].y*xq0.y + wsf[0].z*xq0.z + wsf[0].w*xq0.w
             + wsf[1].x*xq1.x + wsf[1].y*xq1.y + wsf[1].z*xq1.z + wsf[1].w*xq1.w
             + wsf[2].x*xq2.x + wsf[2].y*xq2.y + wsf[2].z*xq2.z + wsf[2].w*xq2.w
             + wsf[3].x*xq3.x + wsf[3].y*xq3.y + wsf[3].z*xq3.z + wsf[3].w*xq3.w;
    acc = __builtin_amdgcn_mfma_f32_16x16x32_bf16(wxf[0], pack8(xq0, xq1), acc, 0, 0, 0);
    acc = __builtin_amdgcn_mfma_f32_16x16x32_bf16(wxf[1], pack8(xq2, xq3), acc, 0, 0, 0);

    const int tn = (t + 1 < NT) ? (t + 1) : t;   // xpref target row
    const float* xrn = x + ((size_t)(b_base + bm)*NT + tn)*ND + w*64 + lg*8;

    if (t > 0) {
      // ---- 2. confirm flag (early-issued at prev tail); retry if stale ----
      asm volatile("s_waitcnt vmcnt(0)" ::: "memory");
      if (!__all((int)(flagv != 0u))) {
        const unsigned int* fp = flags + ((size_t)bg*NT + (t-1))*64 + l;
        do {
          __builtin_amdgcn_s_sleep(1);
          asm volatile("global_load_dword %0, %1, off sc0 sc1\n\t"
                       "s_waitcnt vmcnt(0)"
                       : "=v"(flagv) : "v"(fp) : "memory");
        } while (!__all((int)(flagv != 0u)));
      }
      __builtin_amdgcn_sched_barrier(0);
      // ---- 3. data loads: 8 x dwordx4 (bf16 B-frags) ----
      const unsigned short* hrow =
          hbuf + ((size_t)((t-1)&1)*NB + b_base + bm)*NH + w*256 + lg*8;
      uint4 hv[8];
      #pragma unroll
      for (int m = 0; m < 8; ++m)
        asm volatile("global_load_dwordx4 %0, %1, off sc0 sc1"
                     : "=v"(hv[m]) : "v"(hrow + m*32) : "memory");
      // ---- 4. deferred outputs of step t-1 ----
      {
        const size_t obase = ((size_t)b_glob*NT + (t-1))*NH + rg;
        const float sp  = p_sg * (1.f - p_sg);
        const float rdv = (p_htld - p_hp)*(sp*usr_r) +
                          p_sg*(1.f - p_htld*p_htld)*whd_r;
        const float lv  = 1.f - p_sg;
        asm volatile("global_store_dword %0, %1, off nt"
                     :: "v"(hs_o + obase), "v"(myh) : "memory");
        asm volatile("global_store_dword %0, %1, off nt"
                     :: "v"(g_o + obase), "v"(p_sg) : "memory");
        asm volatile("global_store_dword %0, %1, off nt"
                     :: "v"(l_o + obase), "v"(lv) : "memory");
        asm volatile("global_store_dword %0, %1, off nt"
                     :: "v"(rd_o + obase), "v"(rdv) : "memory");
      }
      // ---- 5. x prefetch for t+1 (retired by tail vmcnt(0)) ----
      asm volatile(
        "global_load_dwordx4 %0, %4, off\n\t"
        "global_load_dwordx4 %1, %4, off offset:16\n\t"
        "global_load_dwordx4 %2, %4, off offset:128\n\t"
        "global_load_dwordx4 %3, %4, off offset:144"
        : "=&v"(xq0), "=&v"(xq1), "=&v"(xq2), "=&v"(xq3)
        : "v"(xrn) : "memory");
      // ---- 6. retire exactly data8 (outs4 + xpref4 keep flying) ----
      asm volatile("s_waitcnt vmcnt(8)" ::: "memory");
      __builtin_amdgcn_sched_barrier(0);
      // ---- 7. h-part: 8 mfma + gate-h ----
      #pragma unroll
      for (int m = 0; m < 8; ++m) {
        acc = __builtin_amdgcn_mfma_f32_16x16x32_bf16(
                whf[m], __builtin_bit_cast(bf16x8, hv[m]), acc, 0, 0, 0);
        const uint4 uu = *(const uint4*)&us_sh[w*256 + m*32 + lg*8];
        ga += bflo(uu.x)*bflo(hv[m].x) + bfhi(uu.x)*bfhi(hv[m].x)
            + bflo(uu.y)*bflo(hv[m].y) + bfhi(uu.y)*bfhi(hv[m].y)
            + bflo(uu.z)*bflo(hv[m].z) + bfhi(uu.z)*bfhi(hv[m].z)
            + bflo(uu.w)*bflo(hv[m].w) + bfhi(uu.w)*bfhi(hv[m].w);
      }
    } else {
      // t == 0: only the x prefetch for t=1
      asm volatile(
        "global_load_dwordx4 %0, %4, off\n\t"
        "global_load_dwordx4 %1, %4, off offset:16\n\t"
        "global_load_dwordx4 %2, %4, off offset:128\n\t"
        "global_load_dwordx4 %3, %4, off offset:144"
        : "=&v"(xq0), "=&v"(xq1), "=&v"(xq2), "=&v"(xq3)
        : "v"(xrn) : "memory");
    }

    // ---- 8. combine partials ----
    ga += __shfl_xor(ga, 16, 64);
    ga += __shfl_xor(ga, 32, 64);
    if (l < 16) gpart[w][l] = ga;
    cpart[w][0][l] = acc[0];
    cpart[w][1][l] = acc[1];
    cpart[w][2][l] = acc[2];
    cpart[w][3][l] = acc[3];
    __syncthreads();                   // barrier (a)

    // ---- 9. epilogue: 1 output per thread (row ro, batch bo) ----
    // C mapping (m89): col(lane&15)=batch, row=(lane>>4)*4+reg
    const float gsum = gpart[0][bo] + gpart[1][bo] + gpart[2][bo] + gpart[3][bo];
    const int ci = ro & 3, cl = ((ro >> 2) << 4) + bo;
    const float pre0 = cpart[0][ci][cl] + cpart[1][ci][cl] +
                       cpart[2][ci][cl] + cpart[3][ci][cl];
    const float sg   = 1.f / (1.f + expf(-(gsum + wsb)));
    const float pre  = pre0 + wxb_r;
    const float htld = tanhf(pre);
    const float hp   = myh;
    const float h    = (1.f - sg)*hp + sg*htld;
    myh = h; p_sg = sg; p_htld = htld; p_hp = hp;
    {
      const unsigned hb = (unsigned)f2bf(h);
      unsigned short* hptr = hbuf + ((size_t)(t & 1)*NB + b_glob)*NH + rg;
      asm volatile("global_store_short %0, %1, off sc0 sc1"
                   :: "v"(hptr), "v"(hb) : "memory");
    }
    // ---- 10. drain everything (h store, outs4, xpref4 — xpref had ~1us) ----
    asm volatile("s_waitcnt vmcnt(0)" ::: "memory");
    __builtin_amdgcn_sched_barrier(0);   // xq regs now final for next iter
    __syncthreads();                   // barrier (b): all h stores at LLC
    // ---- 11/12. own flag store + EARLY flag-row load for next step ----
    if (tid == 0) {
      unsigned int one = 1u;
      unsigned int* fp = flags + ((size_t)bg*NT + t)*64 + sl;
      asm volatile("global_store_dword %0, %1, off sc0 sc1"
                   :: "v"(fp), "v"(one) : "memory");
    }
    {
      const unsigned int* fld = flags + ((size_t)bg*NT + t)*64 + l;
      asm volatile("global_load_dword %0, %1, off sc0 sc1"
                   : "=v"(flagv) : "v"(fld) : "memory");
    }
  }

  // ---- final step's deferred outputs ----
  {
    const size_t obase = ((size_t)b_glob*NT + (NT-1))*NH + rg;
    const float sp  = p_sg * (1.f - p_sg);
    const float rdv = (p_htld - p_hp)*(sp*usr_r) +
                      p_sg*(1.f - p_htld*p_htld)*whd_r;
    __builtin_nontemporal_store(myh, &hs_o[obase]);
    __builtin_nontemporal_store(p_sg, &g_o[obase]);
    __builtin_nontemporal_store(1.f - p_sg, &l_o[obase]);
    __builtin_nontemporal_store(rdv, &rd_o[obase]);
  }
}

// ys[b,t] = out_w . hs[b,t,:] + out_b
__global__ void yfinish_kernel(const float* __restrict__ hs,
                               const float* __restrict__ out_w,
                               const float* __restrict__ out_b,
                               float* __restrict__ ys)
{
  const int row  = (int)blockIdx.x*4 + ((int)threadIdx.x >> 6);
  const int lane = (int)threadIdx.x & 63;
  const float4* hp = (const float4*)(hs + (size_t)row*NH);
  const float4* wp = (const float4*)out_w;
  float s = 0.f;
  #pragma unroll
  for (int i = 0; i < 4; ++i) {
    const float4 h4 = hp[i*64 + lane];
    const float4 w4 = wp[i*64 + lane];
    s += h4.x*w4.x + h4.y*w4.y + h4.z*w4.z + h4.w*w4.w;
  }
  #pragma unroll
  for (int off = 32; off > 0; off >>= 1) s += __shfl_xor(s, off, 64);
  if (lane == 0) ys[row] = s + out_b[0];
}

extern "C" void kernel_launch(void* const* d_in, const int* in_sizes, int n_in,
                              void* d_out, int out_size, void* d_ws, size_t ws_size,
                              hipStream_t stream)
{
  (void)in_sizes; (void)n_in; (void)out_size; (void)ws_size;
  const float* x     = (const float*)d_in[0];
  const float* Wx_w  = (const float*)d_in[1];
  const float* Wx_b  = (const float*)d_in[2];
  const float* Wh_w  = (const float*)d_in[3];
  const float* Ws_w  = (const float*)d_in[4];
  const float* Ws_b  = (const float*)d_in[5];
  const float* Us_w  = (const float*)d_in[6];
  const float* out_w = (const float*)d_in[7];
  const float* out_b = (const float*)d_in[8];
  float* out = (float*)d_out;

  char* ws = (char*)d_ws;
  unsigned short* hbuf = (unsigned short*)ws;                 // bf16, 256 KB
  unsigned int* flags  = (unsigned int*)(ws + 262144);        // 4*512*64*4 = 512 KB

  hipMemsetAsync(flags, 0, (size_t)4*NT*64*sizeof(unsigned int), stream);
  rnn_step_kernel<<<dim3(256), dim3(256), 0, stream>>>(
      x, Wx_w, Wx_b, Wh_w, Ws_w, Ws_b, Us_w, out, hbuf, flags);
  yfinish_kernel<<<dim3((NB*NT)/4), dim3(256), 0, stream>>>(
      out + (size_t)NB*NT, out_w, out_b, out);
}

// Round 15
// 3106.188 us; speedup vs baseline: 1.0432x; 1.0432x over previous
//
#include <hip/hip_runtime.h>

#define NT 512
#define ND 256
#define NH 1024
#define NB 64
// R15 = R11 (best proven: two-phase handoff, deferred outputs, counted vmcnt)
// + ONE change: barrier(b) deleted. Flags become per-WAVE bytes of the per-slice
// u32: producer wave w stores byte w (global_store_byte, disjoint bytes, no RMW)
// right after ITS OWN vmcnt(0) — no cross-wave drain coupling, no 2nd barrier.
// Consumer poll unchanged (1 dword/lane) but checks == 0x01010101.
// Race argument (wave-wise): wave flags t only after its h_{t-1} reads retired
// (vmcnt(4) precedes flag in program order); overwriter of slot t-1 saw ALL
// bytes of flags_t -> every wave's reads of h_{t-1} complete. R14's lesson
// kept: nothing slow sits between h-store and flag store.

typedef float f32x4 __attribute__((ext_vector_type(4)));
typedef short bf16x8 __attribute__((ext_vector_type(8)));

__device__ __forceinline__ unsigned short f2bf(float f) {     // RNE
  unsigned u = __builtin_bit_cast(unsigned, f);
  u += 0x7fffu + ((u >> 16) & 1u);
  return (unsigned short)(u >> 16);
}
__device__ __forceinline__ float bflo(unsigned u) {
  return __builtin_bit_cast(float, u << 16);
}
__device__ __forceinline__ float bfhi(unsigned u) {
  return __builtin_bit_cast(float, u & 0xffff0000u);
}
__device__ __forceinline__ bf16x8 pack8(float4 a, float4 b) {
  bf16x8 r;
  r[0] = (short)f2bf(a.x); r[1] = (short)f2bf(a.y);
  r[2] = (short)f2bf(a.z); r[3] = (short)f2bf(a.w);
  r[4] = (short)f2bf(b.x); r[5] = (short)f2bf(b.y);
  r[6] = (short)f2bf(b.z); r[7] = (short)f2bf(b.w);
  return r;
}

__global__ void __launch_bounds__(256, 1)
rnn_step_kernel(const float* __restrict__ x,
                const float* __restrict__ Wx_w,
                const float* __restrict__ Wx_b,
                const float* __restrict__ Wh_w,
                const float* __restrict__ Ws_w,
                const float* __restrict__ Ws_b,
                const float* __restrict__ Us_w,
                float* __restrict__ out,
                unsigned short* __restrict__ hbuf,   // bf16 [2][NB][NH]
                unsigned int* __restrict__ flags)    // [4][NT][64] (4 bytes/slice)
{
  const int tid = (int)threadIdx.x;
  const int w   = tid >> 6;        // wave
  const int l   = tid & 63;        // lane
  const int bm  = l & 15;          // mfma row/col index for A/B frags
  const int lg  = l >> 4;          // lane group
  const int sl  = (int)blockIdx.x & 63;
  const int bg  = (int)blockIdx.x >> 6;
  const int r_base = sl * 16;
  const int b_base = bg * 16;
  const int ro = tid & 15;         // epilogue: consecutive lanes -> rows
  const int bo = tid >> 4;
  const int rg = r_base + ro;
  const int b_glob = b_base + bo;

  __shared__ unsigned short us_sh[1024];   // bf16 Us (broadcast reads)
  __shared__ float cpart[4][4][72];        // per-wave C partials, padded
  __shared__ float gpart[4][16];           // per-wave gate partials

  // ---- one-time: Us -> bf16 LDS ----
  {
    const float4 uv = *(const float4*)(Us_w + tid*4);
    us_sh[tid*4+0] = f2bf(uv.x); us_sh[tid*4+1] = f2bf(uv.y);
    us_sh[tid*4+2] = f2bf(uv.z); us_sh[tid*4+3] = f2bf(uv.w);
  }

  // ---- A-fragments in registers (bf16), held all 512 steps ----
  // A layout (m89): row = l&15, k = ktile + (l>>4)*8 + j
  bf16x8 whf[8];   // wave w: h-K slice [w*256,+256) -> 8 mfma
  bf16x8 wxf[2];   // wave w: x-K slice [w*64,+64)   -> 2 mfma
  float4 wsf[4];   // Ws f32 slice for gate-x (exact f32 math)
  {
    const int ar = r_base + bm;
    #pragma unroll
    for (int m = 0; m < 8; ++m) {
      const int k0 = w*256 + m*32 + lg*8;
      const float4 f0 = *(const float4*)(Wh_w + (size_t)ar*NH + k0);
      const float4 f1 = *(const float4*)(Wh_w + (size_t)ar*NH + k0 + 4);
      whf[m] = pack8(f0, f1);
    }
    #pragma unroll
    for (int m = 0; m < 2; ++m) {
      const int k0 = w*64 + m*32 + lg*8;
      const float4 f0 = *(const float4*)(Wx_w + (size_t)ar*ND + k0);
      const float4 f1 = *(const float4*)(Wx_w + (size_t)ar*ND + k0 + 4);
      wxf[m] = pack8(f0, f1);
      wsf[m*2]   = *(const float4*)(Ws_w + k0);
      wsf[m*2+1] = *(const float4*)(Ws_w + k0 + 4);
    }
  }
  const float wxb_r = Wx_b[rg];
  const float whd_r = Wh_w[(size_t)rg*NH + rg];
  const float usr_r = Us_w[rg];
  const float wsb   = Ws_b[0];

  float* const hs_o = out + (size_t)NB*NT;
  float* const g_o  = hs_o + (size_t)NB*NT*NH;
  float* const l_o  = g_o  + (size_t)NB*NT*NH;
  float* const rd_o = l_o  + (size_t)NB*NT*NH;

  __syncthreads();

  float myh = 0.f;
  float p_sg = 0.f, p_htld = 0.f, p_hp = 0.f;

  for (int t = 0; t < NT; ++t) {
    // ---- x-part: direct f32 loads, in-reg pack, 2 mfma + gate-x (f32) ----
    f32x4 acc = {0.f, 0.f, 0.f, 0.f};
    float ga = 0.f;
    {
      const float* xrow = x + ((size_t)(b_base+bm)*NT + t)*ND + w*64 + lg*8;
      #pragma unroll
      for (int m = 0; m < 2; ++m) {
        const float4 f0 = *(const float4*)(xrow + m*32);
        const float4 f1 = *(const float4*)(xrow + m*32 + 4);
        acc = __builtin_amdgcn_mfma_f32_16x16x32_bf16(
                wxf[m], pack8(f0, f1), acc, 0, 0, 0);
        ga += wsf[m*2].x*f0.x + wsf[m*2].y*f0.y + wsf[m*2].z*f0.z + wsf[m*2].w*f0.w
            + wsf[m*2+1].x*f1.x + wsf[m*2+1].y*f1.y + wsf[m*2+1].z*f1.z + wsf[m*2+1].w*f1.w;
      }
    }

    // ---- wait for h_{t-1}: poll per-slice dword (4 wave-bytes) ----
    if (t > 0) {
      {
        const unsigned int* fp = flags + ((size_t)bg*NT + (t-1))*64 + l;
        while (true) {
          unsigned int v;
          asm volatile("global_load_dword %0, %1, off sc0 sc1\n\t"
                       "s_waitcnt vmcnt(0)"
                       : "=v"(v) : "v"(fp) : "memory");
          if (__all((int)(v == 0x01010101u))) break;
          __builtin_amdgcn_s_sleep(1);
        }
      }
      __builtin_amdgcn_sched_barrier(0);
      // ---- data loads: 8 x dwordx4 (bf16 B-frags) ----
      const unsigned short* hrow =
          hbuf + ((size_t)((t-1)&1)*NB + b_base + bm)*NH + w*256 + lg*8;
      uint4 hv[8];
      #pragma unroll
      for (int m = 0; m < 8; ++m)
        asm volatile("global_load_dwordx4 %0, %1, off sc0 sc1"
                     : "=v"(hv[m]) : "v"(hrow + m*32) : "memory");
      // ---- deferred outputs of step t-1 (after data8; drain at tail) ----
      {
        const size_t obase = ((size_t)b_glob*NT + (t-1))*NH + rg;
        const float sp  = p_sg * (1.f - p_sg);
        const float rdv = (p_htld - p_hp)*(sp*usr_r) +
                          p_sg*(1.f - p_htld*p_htld)*whd_r;
        const float lv  = 1.f - p_sg;
        asm volatile("global_store_dword %0, %1, off nt"
                     :: "v"(hs_o + obase), "v"(myh) : "memory");
        asm volatile("global_store_dword %0, %1, off nt"
                     :: "v"(g_o + obase), "v"(p_sg) : "memory");
        asm volatile("global_store_dword %0, %1, off nt"
                     :: "v"(l_o + obase), "v"(lv) : "memory");
        asm volatile("global_store_dword %0, %1, off nt"
                     :: "v"(rd_o + obase), "v"(rdv) : "memory");
      }
      // ---- counted wait: data8 retired, outs4 still in flight ----
      asm volatile("s_waitcnt vmcnt(4)" ::: "memory");
      __builtin_amdgcn_sched_barrier(0);
      // ---- h-part: 8 mfma + gate-h ----
      #pragma unroll
      for (int m = 0; m < 8; ++m) {
        acc = __builtin_amdgcn_mfma_f32_16x16x32_bf16(
                whf[m], __builtin_bit_cast(bf16x8, hv[m]), acc, 0, 0, 0);
        const uint4 uu = *(const uint4*)&us_sh[w*256 + m*32 + lg*8];
        ga += bflo(uu.x)*bflo(hv[m].x) + bfhi(uu.x)*bfhi(hv[m].x)
            + bflo(uu.y)*bflo(hv[m].y) + bfhi(uu.y)*bfhi(hv[m].y)
            + bflo(uu.z)*bflo(hv[m].z) + bfhi(uu.z)*bfhi(hv[m].z)
            + bflo(uu.w)*bflo(hv[m].w) + bfhi(uu.w)*bfhi(hv[m].w);
      }
    }

    // ---- combine partials ----
    ga += __shfl_xor(ga, 16, 64);
    ga += __shfl_xor(ga, 32, 64);
    if (l < 16) gpart[w][l] = ga;
    cpart[w][0][l] = acc[0];
    cpart[w][1][l] = acc[1];
    cpart[w][2][l] = acc[2];
    cpart[w][3][l] = acc[3];
    __syncthreads();                   // barrier (a) — the ONLY barrier per step

    // ---- epilogue: 1 output per thread (row ro, batch bo) ----
    // C mapping (m89): col(lane&15)=batch, row=(lane>>4)*4+reg
    const float gsum = gpart[0][bo] + gpart[1][bo] + gpart[2][bo] + gpart[3][bo];
    const int ci = ro & 3, cl = ((ro >> 2) << 4) + bo;
    const float pre0 = cpart[0][ci][cl] + cpart[1][ci][cl] +
                       cpart[2][ci][cl] + cpart[3][ci][cl];
    const float sg   = 1.f / (1.f + expf(-(gsum + wsb)));
    const float pre  = pre0 + wxb_r;
    const float htld = tanhf(pre);
    const float hp   = myh;
    const float h    = (1.f - sg)*hp + sg*htld;
    myh = h; p_sg = sg; p_htld = htld; p_hp = hp;
    {
      const unsigned hb = (unsigned)f2bf(h);
      unsigned short* hptr = hbuf + ((size_t)(t & 1)*NB + b_glob)*NH + rg;
      asm volatile("global_store_short %0, %1, off sc0 sc1"
                   :: "v"(hptr), "v"(hb) : "memory");
    }
    // ---- per-WAVE readiness: own-wave drain, then own flag byte. NO barrier. ----
    asm volatile("s_waitcnt vmcnt(0)" ::: "memory");
    if (l == 0) {
      unsigned char* fb =
          (unsigned char*)(flags + ((size_t)bg*NT + t)*64 + sl) + w;
      const unsigned one = 1u;
      asm volatile("global_store_byte %0, %1, off sc0 sc1"
                   :: "v"(fb), "v"(one) : "memory");
    }
  }

  // ---- final step's deferred outputs ----
  {
    const size_t obase = ((size_t)b_glob*NT + (NT-1))*NH + rg;
    const float sp  = p_sg * (1.f - p_sg);
    const float rdv = (p_htld - p_hp)*(sp*usr_r) +
                      p_sg*(1.f - p_htld*p_htld)*whd_r;
    __builtin_nontemporal_store(myh, &hs_o[obase]);
    __builtin_nontemporal_store(p_sg, &g_o[obase]);
    __builtin_nontemporal_store(1.f - p_sg, &l_o[obase]);
    __builtin_nontemporal_store(rdv, &rd_o[obase]);
  }
}

// ys[b,t] = out_w . hs[b,t,:] + out_b
__global__ void yfinish_kernel(const float* __restrict__ hs,
                               const float* __restrict__ out_w,
                               const float* __restrict__ out_b,
                               float* __restrict__ ys)
{
  const int row  = (int)blockIdx.x*4 + ((int)threadIdx.x >> 6);
  const int lane = (int)threadIdx.x & 63;
  const float4* hp = (const float4*)(hs + (size_t)row*NH);
  const float4* wp = (const float4*)out_w;
  float s = 0.f;
  #pragma unroll
  for (int i = 0; i < 4; ++i) {
    const float4 h4 = hp[i*64 + lane];
    const float4 w4 = wp[i*64 + lane];
    s += h4.x*w4.x + h4.y*w4.y + h4.z*w4.z + h4.w*w4.w;
  }
  #pragma unroll
  for (int off = 32; off > 0; off >>= 1) s += __shfl_xor(s, off, 64);
  if (lane == 0) ys[row] = s + out_b[0];
}

extern "C" void kernel_launch(void* const* d_in, const int* in_sizes, int n_in,
                              void* d_out, int out_size, void* d_ws, size_t ws_size,
                              hipStream_t stream)
{
  (void)in_sizes; (void)n_in; (void)out_size; (void)ws_size;
  const float* x     = (const float*)d_in[0];
  const float* Wx_w  = (const float*)d_in[1];
  const float* Wx_b  = (const float*)d_in[2];
  const float* Wh_w  = (const float*)d_in[3];
  const float* Ws_w  = (const float*)d_in[4];
  const float* Ws_b  = (const float*)d_in[5];
  const float* Us_w  = (const float*)d_in[6];
  const float* out_w = (const float*)d_in[7];
  const float* out_b = (const float*)d_in[8];
  float* out = (float*)d_out;

  char* ws = (char*)d_ws;
  unsigned short* hbuf = (unsigned short*)ws;                 // bf16, 256 KB
  unsigned int* flags  = (unsigned int*)(ws + 262144);        // 4*512*64*4 = 512 KB

  hipMemsetAsync(flags, 0, (size_t)4*NT*64*sizeof(unsigned int), stream);
  rnn_step_kernel<<<dim3(256), dim3(256), 0, stream>>>(
      x, Wx_w, Wx_b, Wh_w, Ws_w, Ws_b, Us_w, out, hbuf, flags);
  yfinish_kernel<<<dim3((NB*NT)/4), dim3(256), 0, stream>>>(
      out + (size_t)NB*NT, out_w, out_b, out);
}

// Round 17
// 2674.037 us; speedup vs baseline: 1.2118x; 1.1616x over previous
//
#include <hip/hip_runtime.h>

#define NT 512
#define ND 256
#define NH 1024
#define NB 64
// R17 = R16 with the b_base_init compile fix (inline bg*16).
// R16 theory: R11 + x-prefetch with CORRECT vmcnt issue-ordering:
//   epilogue issues [h-store, xpref4, outs4]; vmcnt(8) retires h-store ONLY;
//   barrier(b); flag. Next step top: [xpref4, outs4, (fstore)] -> w0 vmcnt(5) /
//   others vmcnt(4) retires xpref4 without waiting outs-acks (in-order retire).
//   x HBM miss (~900cy) ages through h-ack+barrier -> ~250cy residual.
//   Outputs in current-step epilogue. Poll identical to R11 (fast-path kept).
// R15 lesson: flag transition must be ONE dword store after barrier(b).

typedef float f32x4 __attribute__((ext_vector_type(4)));
typedef short bf16x8 __attribute__((ext_vector_type(8)));

__device__ __forceinline__ unsigned short f2bf(float f) {     // RNE
  unsigned u = __builtin_bit_cast(unsigned, f);
  u += 0x7fffu + ((u >> 16) & 1u);
  return (unsigned short)(u >> 16);
}
__device__ __forceinline__ float bflo(unsigned u) {
  return __builtin_bit_cast(float, u << 16);
}
__device__ __forceinline__ float bfhi(unsigned u) {
  return __builtin_bit_cast(float, u & 0xffff0000u);
}
__device__ __forceinline__ bf16x8 pack8(float4 a, float4 b) {
  bf16x8 r;
  r[0] = (short)f2bf(a.x); r[1] = (short)f2bf(a.y);
  r[2] = (short)f2bf(a.z); r[3] = (short)f2bf(a.w);
  r[4] = (short)f2bf(b.x); r[5] = (short)f2bf(b.y);
  r[6] = (short)f2bf(b.z); r[7] = (short)f2bf(b.w);
  return r;
}

__global__ void __launch_bounds__(256, 1)
rnn_step_kernel(const float* __restrict__ x,
                const float* __restrict__ Wx_w,
                const float* __restrict__ Wx_b,
                const float* __restrict__ Wh_w,
                const float* __restrict__ Ws_w,
                const float* __restrict__ Ws_b,
                const float* __restrict__ Us_w,
                float* __restrict__ out,
                unsigned short* __restrict__ hbuf,   // bf16 [2][NB][NH]
                unsigned int* __restrict__ flags)    // [4][NT][64]
{
  const int tid = (int)threadIdx.x;
  const int w   = tid >> 6;        // wave
  const int l   = tid & 63;        // lane
  const int bm  = l & 15;          // mfma row/col index for A/B frags
  const int lg  = l >> 4;          // lane group
  const int sl  = (int)blockIdx.x & 63;
  const int bg  = (int)blockIdx.x >> 6;
  const int r_base = sl * 16;
  const int b_base = bg * 16;
  const int ro = tid & 15;         // epilogue: consecutive lanes -> rows
  const int bo = tid >> 4;
  const int rg = r_base + ro;
  const int b_glob = b_base + bo;

  __shared__ unsigned short us_sh[1024];   // bf16 Us (broadcast reads)
  __shared__ float cpart[4][4][72];        // per-wave C partials, padded
  __shared__ float gpart[4][16];           // per-wave gate partials

  // ---- one-time: Us -> bf16 LDS ----
  {
    const float4 uv = *(const float4*)(Us_w + tid*4);
    us_sh[tid*4+0] = f2bf(uv.x); us_sh[tid*4+1] = f2bf(uv.y);
    us_sh[tid*4+2] = f2bf(uv.z); us_sh[tid*4+3] = f2bf(uv.w);
  }

  // ---- A-fragments in registers (bf16), held all 512 steps ----
  // A layout (m89): row = l&15, k = ktile + (l>>4)*8 + j
  bf16x8 whf[8];   // wave w: h-K slice [w*256,+256) -> 8 mfma
  bf16x8 wxf[2];   // wave w: x-K slice [w*64,+64)   -> 2 mfma
  float4 wsf[4];   // Ws f32 slice for gate-x (exact f32 math)
  {
    const int ar = r_base + bm;
    #pragma unroll
    for (int m = 0; m < 8; ++m) {
      const int k0 = w*256 + m*32 + lg*8;
      const float4 f0 = *(const float4*)(Wh_w + (size_t)ar*NH + k0);
      const float4 f1 = *(const float4*)(Wh_w + (size_t)ar*NH + k0 + 4);
      whf[m] = pack8(f0, f1);
    }
    #pragma unroll
    for (int m = 0; m < 2; ++m) {
      const int k0 = w*64 + m*32 + lg*8;
      const float4 f0 = *(const float4*)(Wx_w + (size_t)ar*ND + k0);
      const float4 f1 = *(const float4*)(Wx_w + (size_t)ar*ND + k0 + 4);
      wxf[m] = pack8(f0, f1);
      wsf[m*2]   = *(const float4*)(Ws_w + k0);
      wsf[m*2+1] = *(const float4*)(Ws_w + k0 + 4);
    }
  }
  const float wxb_r = Wx_b[rg];
  const float whd_r = Wh_w[(size_t)rg*NH + rg];
  const float usr_r = Us_w[rg];
  const float wsb   = Ws_b[0];

  float* const hs_o = out + (size_t)NB*NT;
  float* const g_o  = hs_o + (size_t)NB*NT*NH;
  float* const l_o  = g_o  + (size_t)NB*NT*NH;
  float* const rd_o = l_o  + (size_t)NB*NT*NH;

  __syncthreads();

  float myh = 0.f;
  float4 xq0, xq1, xq2, xq3;     // x for the CURRENT step (prefetched)

  // ---- prologue: x_0 into registers (drained) ----
  {
    const float* xr = x + ((size_t)(b_base + bm)*NT + 0)*ND + w*64 + lg*8;
    asm volatile(
      "global_load_dwordx4 %0, %4, off\n\t"
      "global_load_dwordx4 %1, %4, off offset:16\n\t"
      "global_load_dwordx4 %2, %4, off offset:128\n\t"
      "global_load_dwordx4 %3, %4, off offset:144\n\t"
      "s_waitcnt vmcnt(0)"
      : "=&v"(xq0), "=&v"(xq1), "=&v"(xq2), "=&v"(xq3)
      : "v"(xr) : "memory");
    __builtin_amdgcn_sched_barrier(0);
  }

  for (int t = 0; t < NT; ++t) {
    // ---- 0. x-wait: retire xpref4 only (outs4/fstore keep flying) ----
    if (t > 0) {
      if (w == 0) asm volatile("s_waitcnt vmcnt(5)" ::: "memory");
      else        asm volatile("s_waitcnt vmcnt(4)" ::: "memory");
      __builtin_amdgcn_sched_barrier(0);
    }

    // ---- 1. x-part from prefetched regs: 2 mfma + gate-x (f32) ----
    f32x4 acc = {0.f, 0.f, 0.f, 0.f};
    float ga = wsf[0].x*xq0.x + wsf[0].y*xq0.y + wsf[0].z*xq0.z + wsf[0].w*xq0.w
             + wsf[1].x*xq1.x + wsf[1].y*xq1.y + wsf[1].z*xq1.z + wsf[1].w*xq1.w
             + wsf[2].x*xq2.x + wsf[2].y*xq2.y + wsf[2].z*xq2.z + wsf[2].w*xq2.w
             + wsf[3].x*xq3.x + wsf[3].y*xq3.y + wsf[3].z*xq3.z + wsf[3].w*xq3.w;
    acc = __builtin_amdgcn_mfma_f32_16x16x32_bf16(wxf[0], pack8(xq0, xq1), acc, 0, 0, 0);
    acc = __builtin_amdgcn_mfma_f32_16x16x32_bf16(wxf[1], pack8(xq2, xq3), acc, 0, 0, 0);

    const int tn = (t + 1 < NT) ? (t + 1) : t;
    const float* xrn = x + ((size_t)(b_base + bm)*NT + tn)*ND + w*64 + lg*8;

    // ---- 2. poll h_{t-1} flags (R11 verbatim: fast-path first load) ----
    if (t > 0) {
      {
        const unsigned int* fp = flags + ((size_t)bg*NT + (t-1))*64 + l;
        while (true) {
          unsigned int v;
          asm volatile("global_load_dword %0, %1, off sc0 sc1\n\t"
                       "s_waitcnt vmcnt(0)"
                       : "=v"(v) : "v"(fp) : "memory");
          if (__all((int)(v != 0u))) break;
          __builtin_amdgcn_s_sleep(1);
        }
      }
      __builtin_amdgcn_sched_barrier(0);
      // ---- 3. data loads: 8 x dwordx4 (bf16 B-frags) ----
      const unsigned short* hrow =
          hbuf + ((size_t)((t-1)&1)*NB + b_base + bm)*NH + w*256 + lg*8;
      uint4 hv[8];
      #pragma unroll
      for (int m = 0; m < 8; ++m)
        asm volatile("global_load_dwordx4 %0, %1, off sc0 sc1"
                     : "=v"(hv[m]) : "v"(hrow + m*32) : "memory");
      asm volatile("s_waitcnt vmcnt(0)" ::: "memory");
      __builtin_amdgcn_sched_barrier(0);
      // ---- 4. h-part: 8 mfma + gate-h ----
      #pragma unroll
      for (int m = 0; m < 8; ++m) {
        acc = __builtin_amdgcn_mfma_f32_16x16x32_bf16(
                whf[m], __builtin_bit_cast(bf16x8, hv[m]), acc, 0, 0, 0);
        const uint4 uu = *(const uint4*)&us_sh[w*256 + m*32 + lg*8];
        ga += bflo(uu.x)*bflo(hv[m].x) + bfhi(uu.x)*bfhi(hv[m].x)
            + bflo(uu.y)*bflo(hv[m].y) + bfhi(uu.y)*bfhi(hv[m].y)
            + bflo(uu.z)*bflo(hv[m].z) + bfhi(uu.z)*bfhi(hv[m].z)
            + bflo(uu.w)*bflo(hv[m].w) + bfhi(uu.w)*bfhi(hv[m].w);
      }
    }

    // ---- 5. combine partials ----
    ga += __shfl_xor(ga, 16, 64);
    ga += __shfl_xor(ga, 32, 64);
    if (l < 16) gpart[w][l] = ga;
    cpart[w][0][l] = acc[0];
    cpart[w][1][l] = acc[1];
    cpart[w][2][l] = acc[2];
    cpart[w][3][l] = acc[3];
    __syncthreads();                   // barrier (a)

    // ---- 6. epilogue: 1 output per thread (row ro, batch bo) ----
    // C mapping (m89): col(lane&15)=batch, row=(lane>>4)*4+reg
    const float gsum = gpart[0][bo] + gpart[1][bo] + gpart[2][bo] + gpart[3][bo];
    const int ci = ro & 3, cl = ((ro >> 2) << 4) + bo;
    const float pre0 = cpart[0][ci][cl] + cpart[1][ci][cl] +
                       cpart[2][ci][cl] + cpart[3][ci][cl];
    const float sg   = 1.f / (1.f + expf(-(gsum + wsb)));
    const float pre  = pre0 + wxb_r;
    const float htld = tanhf(pre);
    const float hp   = myh;
    const float h    = (1.f - sg)*hp + sg*htld;
    myh = h;
    // ---- 7. VMEM issue order: [h-store][xpref4][outs4] (h oldest) ----
    {
      const unsigned hb = (unsigned)f2bf(h);
      unsigned short* hptr = hbuf + ((size_t)(t & 1)*NB + b_glob)*NH + rg;
      asm volatile("global_store_short %0, %1, off sc0 sc1"
                   :: "v"(hptr), "v"(hb) : "memory");
    }
    asm volatile(
      "global_load_dwordx4 %0, %4, off\n\t"
      "global_load_dwordx4 %1, %4, off offset:16\n\t"
      "global_load_dwordx4 %2, %4, off offset:128\n\t"
      "global_load_dwordx4 %3, %4, off offset:144"
      : "=&v"(xq0), "=&v"(xq1), "=&v"(xq2), "=&v"(xq3)
      : "v"(xrn) : "memory");
    {
      const size_t obase = ((size_t)b_glob*NT + t)*NH + rg;
      const float sp  = sg * (1.f - sg);
      const float rdv = (htld - hp)*(sp*usr_r) + sg*(1.f - htld*htld)*whd_r;
      const float lv  = 1.f - sg;
      asm volatile("global_store_dword %0, %1, off nt"
                   :: "v"(hs_o + obase), "v"(h) : "memory");
      asm volatile("global_store_dword %0, %1, off nt"
                   :: "v"(g_o + obase), "v"(sg) : "memory");
      asm volatile("global_store_dword %0, %1, off nt"
                   :: "v"(l_o + obase), "v"(lv) : "memory");
      asm volatile("global_store_dword %0, %1, off nt"
                   :: "v"(rd_o + obase), "v"(rdv) : "memory");
    }
    // ---- 8. retire h-store ONLY (9 outstanding -> 8); then publish ----
    asm volatile("s_waitcnt vmcnt(8)" ::: "memory");
    __builtin_amdgcn_sched_barrier(0);
    __syncthreads();                   // barrier (b): all h stores at LLC
    if (tid == 0) {
      unsigned int one = 1u;
      unsigned int* fp = flags + ((size_t)bg*NT + t)*64 + sl;
      asm volatile("global_store_dword %0, %1, off sc0 sc1"
                   :: "v"(fp), "v"(one) : "memory");
    }
  }
}

// ys[b,t] = out_w . hs[b,t,:] + out_b
__global__ void yfinish_kernel(const float* __restrict__ hs,
                               const float* __restrict__ out_w,
                               const float* __restrict__ out_b,
                               float* __restrict__ ys)
{
  const int row  = (int)blockIdx.x*4 + ((int)threadIdx.x >> 6);
  const int lane = (int)threadIdx.x & 63;
  const float4* hp = (const float4*)(hs + (size_t)row*NH);
  const float4* wp = (const float4*)out_w;
  float s = 0.f;
  #pragma unroll
  for (int i = 0; i < 4; ++i) {
    const float4 h4 = hp[i*64 + lane];
    const float4 w4 = wp[i*64 + lane];
    s += h4.x*w4.x + h4.y*w4.y + h4.z*w4.z + h4.w*w4.w;
  }
  #pragma unroll
  for (int off = 32; off > 0; off >>= 1) s += __shfl_xor(s, off, 64);
  if (lane == 0) ys[row] = s + out_b[0];
}

extern "C" void kernel_launch(void* const* d_in, const int* in_sizes, int n_in,
                              void* d_out, int out_size, void* d_ws, size_t ws_size,
                              hipStream_t stream)
{
  (void)in_sizes; (void)n_in; (void)out_size; (void)ws_size;
  const float* x     = (const float*)d_in[0];
  const float* Wx_w  = (const float*)d_in[1];
  const float* Wx_b  = (const float*)d_in[2];
  const float* Wh_w  = (const float*)d_in[3];
  const float* Ws_w  = (const float*)d_in[4];
  const float* Ws_b  = (const float*)d_in[5];
  const float* Us_w  = (const float*)d_in[6];
  const float* out_w = (const float*)d_in[7];
  const float* out_b = (const float*)d_in[8];
  float* out = (float*)d_out;

  char* ws = (char*)d_ws;
  unsigned short* hbuf = (unsigned short*)ws;                 // bf16, 256 KB
  unsigned int* flags  = (unsigned int*)(ws + 262144);        // 4*512*64*4 = 512 KB

  (void)hipMemsetAsync(flags, 0, (size_t)4*NT*64*sizeof(unsigned int), stream);
  rnn_step_kernel<<<dim3(256), dim3(256), 0, stream>>>(
      x, Wx_w, Wx_b, Wh_w, Ws_w, Ws_b, Us_w, out, hbuf, flags);
  yfinish_kernel<<<dim3((NB*NT)/4), dim3(256), 0, stream>>>(
      out + (size_t)NB*NT, out_w, out_b, out);
}

// Round 19
// 1828.854 us; speedup vs baseline: 1.7718x; 1.4621x over previous
//
#include <hip/hip_runtime.h>

#define NT 512
#define ND 256
#define NH 1024
#define NB 64
// R19 = R11 restored verbatim (session best: 1819 us).
// Two-phase handoff (cheap flag detect + bf16 payload), staging-free MFMA,
// deferred output stores (issued mid-step after data8 — the proven-safe slot),
// counted vmcnt(4), 2 barriers/step, sc0 sc1 LLC scope everywhere.
// 18-round ledger: R12 bandwidth-halving, R13 XCD-scope, R14/R17 tail-issued
// prefetch, R15 byte-flags, R18 speculative-tagged all regressed or hung.
// The step floor is cross-wg LLC round-trip latency + producer skew, not
// bandwidth, not compute. This structure is converged.

typedef float f32x4 __attribute__((ext_vector_type(4)));
typedef short bf16x8 __attribute__((ext_vector_type(8)));

__device__ __forceinline__ unsigned short f2bf(float f) {     // RNE
  unsigned u = __builtin_bit_cast(unsigned, f);
  u += 0x7fffu + ((u >> 16) & 1u);
  return (unsigned short)(u >> 16);
}
__device__ __forceinline__ float bflo(unsigned u) {
  return __builtin_bit_cast(float, u << 16);
}
__device__ __forceinline__ float bfhi(unsigned u) {
  return __builtin_bit_cast(float, u & 0xffff0000u);
}
__device__ __forceinline__ bf16x8 pack8(float4 a, float4 b) {
  bf16x8 r;
  r[0] = (short)f2bf(a.x); r[1] = (short)f2bf(a.y);
  r[2] = (short)f2bf(a.z); r[3] = (short)f2bf(a.w);
  r[4] = (short)f2bf(b.x); r[5] = (short)f2bf(b.y);
  r[6] = (short)f2bf(b.z); r[7] = (short)f2bf(b.w);
  return r;
}

__global__ void __launch_bounds__(256, 1)
rnn_step_kernel(const float* __restrict__ x,
                const float* __restrict__ Wx_w,
                const float* __restrict__ Wx_b,
                const float* __restrict__ Wh_w,
                const float* __restrict__ Ws_w,
                const float* __restrict__ Ws_b,
                const float* __restrict__ Us_w,
                float* __restrict__ out,
                unsigned short* __restrict__ hbuf,   // bf16 [2][NB][NH]
                unsigned int* __restrict__ flags)    // [4][NT][64]
{
  const int tid = (int)threadIdx.x;
  const int w   = tid >> 6;        // wave
  const int l   = tid & 63;        // lane
  const int bm  = l & 15;          // mfma row/col index for A/B frags
  const int lg  = l >> 4;          // lane group
  const int sl  = (int)blockIdx.x & 63;
  const int bg  = (int)blockIdx.x >> 6;
  const int r_base = sl * 16;
  const int b_base = bg * 16;
  const int ro = tid & 15;         // epilogue: consecutive lanes -> rows
  const int bo = tid >> 4;
  const int rg = r_base + ro;
  const int b_glob = b_base + bo;

  __shared__ unsigned short us_sh[1024];   // bf16 Us (broadcast reads)
  __shared__ float cpart[4][4][72];        // per-wave C partials, padded
  __shared__ float gpart[4][16];           // per-wave gate partials

  // ---- one-time: Us -> bf16 LDS ----
  {
    const float4 uv = *(const float4*)(Us_w + tid*4);
    us_sh[tid*4+0] = f2bf(uv.x); us_sh[tid*4+1] = f2bf(uv.y);
    us_sh[tid*4+2] = f2bf(uv.z); us_sh[tid*4+3] = f2bf(uv.w);
  }

  // ---- A-fragments in registers (bf16), held all 512 steps ----
  // A layout (m89): row = l&15, k = ktile + (l>>4)*8 + j
  bf16x8 whf[8];   // wave w: h-K slice [w*256, w*256+256) -> 8 mfma
  bf16x8 wxf[2];   // wave w: x-K slice [w*64, w*64+64)    -> 2 mfma
  float4 wsf[4];   // Ws f32 slice for gate-x (exact f32 math)
  {
    const int ar = r_base + bm;
    #pragma unroll
    for (int m = 0; m < 8; ++m) {
      const int k0 = w*256 + m*32 + lg*8;
      const float4 f0 = *(const float4*)(Wh_w + (size_t)ar*NH + k0);
      const float4 f1 = *(const float4*)(Wh_w + (size_t)ar*NH + k0 + 4);
      whf[m] = pack8(f0, f1);
    }
    #pragma unroll
    for (int m = 0; m < 2; ++m) {
      const int k0 = w*64 + m*32 + lg*8;
      const float4 f0 = *(const float4*)(Wx_w + (size_t)ar*ND + k0);
      const float4 f1 = *(const float4*)(Wx_w + (size_t)ar*ND + k0 + 4);
      wxf[m] = pack8(f0, f1);
      wsf[m*2]   = *(const float4*)(Ws_w + k0);
      wsf[m*2+1] = *(const float4*)(Ws_w + k0 + 4);
    }
  }
  const float wxb_r = Wx_b[rg];
  const float whd_r = Wh_w[(size_t)rg*NH + rg];
  const float usr_r = Us_w[rg];
  const float wsb   = Ws_b[0];

  float* const hs_o = out + (size_t)NB*NT;
  float* const g_o  = hs_o + (size_t)NB*NT*NH;
  float* const l_o  = g_o  + (size_t)NB*NT*NH;
  float* const rd_o = l_o  + (size_t)NB*NT*NH;

  __syncthreads();

  float myh = 0.f;           // h_{t-1} for this (row,batch) — also deferred h out
  float p_sg = 0.f, p_htld = 0.f, p_hp = 0.f;   // step t-1 epilogue values

  for (int t = 0; t < NT; ++t) {
    // ---- x-part: direct f32 loads, in-reg pack, 2 mfma + gate-x (f32) ----
    f32x4 acc = {0.f, 0.f, 0.f, 0.f};
    float ga = 0.f;
    {
      const float* xrow = x + ((size_t)(b_base+bm)*NT + t)*ND + w*64 + lg*8;
      #pragma unroll
      for (int m = 0; m < 2; ++m) {
        const float4 f0 = *(const float4*)(xrow + m*32);
        const float4 f1 = *(const float4*)(xrow + m*32 + 4);
        acc = __builtin_amdgcn_mfma_f32_16x16x32_bf16(
                wxf[m], pack8(f0, f1), acc, 0, 0, 0);
        ga += wsf[m*2].x*f0.x + wsf[m*2].y*f0.y + wsf[m*2].z*f0.z + wsf[m*2].w*f0.w
            + wsf[m*2+1].x*f1.x + wsf[m*2+1].y*f1.y + wsf[m*2+1].z*f1.z + wsf[m*2+1].w*f1.w;
      }
    }

    // ---- wait for h_{t-1} (all waves poll; poll path free of HBM acks) ----
    if (t > 0) {
      {
        const unsigned int* fp = flags + ((size_t)bg*NT + (t-1))*64 + l;
        while (true) {
          unsigned int v;
          asm volatile("global_load_dword %0, %1, off sc0 sc1\n\t"
                       "s_waitcnt vmcnt(0)"
                       : "=v"(v) : "v"(fp) : "memory");
          if (__all((int)(v != 0u))) break;
          __builtin_amdgcn_s_sleep(1);
        }
      }
      __builtin_amdgcn_sched_barrier(0);   // pin x-loads out of counted window
      // ---- data loads: 8 x dwordx4 (bf16 B-frags) ----
      const unsigned short* hrow =
          hbuf + ((size_t)((t-1)&1)*NB + b_base + bm)*NH + w*256 + lg*8;
      uint4 hv[8];
      #pragma unroll
      for (int m = 0; m < 8; ++m)
        asm volatile("global_load_dwordx4 %0, %1, off sc0 sc1"
                     : "=v"(hv[m]) : "v"(hrow + m*32) : "memory");
      // ---- DEFERRED outputs of step t-1 (issued after data8; drain at tail) ----
      {
        const size_t obase = ((size_t)b_glob*NT + (t-1))*NH + rg;
        const float sp  = p_sg * (1.f - p_sg);
        const float rdv = (p_htld - p_hp)*(sp*usr_r) +
                          p_sg*(1.f - p_htld*p_htld)*whd_r;
        const float lv  = 1.f - p_sg;
        asm volatile("global_store_dword %0, %1, off nt"
                     :: "v"(hs_o + obase), "v"(myh) : "memory");
        asm volatile("global_store_dword %0, %1, off nt"
                     :: "v"(g_o + obase), "v"(p_sg) : "memory");
        asm volatile("global_store_dword %0, %1, off nt"
                     :: "v"(l_o + obase), "v"(lv) : "memory");
        asm volatile("global_store_dword %0, %1, off nt"
                     :: "v"(rd_o + obase), "v"(rdv) : "memory");
      }
      // ---- counted wait: data8 retired, outs4 still in flight ----
      asm volatile("s_waitcnt vmcnt(4)" ::: "memory");
      __builtin_amdgcn_sched_barrier(0);
      // ---- h-part: 8 mfma + gate-h ----
      #pragma unroll
      for (int m = 0; m < 8; ++m) {
        acc = __builtin_amdgcn_mfma_f32_16x16x32_bf16(
                whf[m], __builtin_bit_cast(bf16x8, hv[m]), acc, 0, 0, 0);
        const uint4 uu = *(const uint4*)&us_sh[w*256 + m*32 + lg*8];
        ga += bflo(uu.x)*bflo(hv[m].x) + bfhi(uu.x)*bfhi(hv[m].x)
            + bflo(uu.y)*bflo(hv[m].y) + bfhi(uu.y)*bfhi(hv[m].y)
            + bflo(uu.z)*bflo(hv[m].z) + bfhi(uu.z)*bfhi(hv[m].z)
            + bflo(uu.w)*bflo(hv[m].w) + bfhi(uu.w)*bfhi(hv[m].w);
      }
    }

    // ---- combine partials ----
    ga += __shfl_xor(ga, 16, 64);
    ga += __shfl_xor(ga, 32, 64);
    if (l < 16) gpart[w][l] = ga;
    cpart[w][0][l] = acc[0];
    cpart[w][1][l] = acc[1];
    cpart[w][2][l] = acc[2];
    cpart[w][3][l] = acc[3];
    __syncthreads();                   // barrier (a)

    // ---- epilogue: 1 output per thread (row ro, batch bo) ----
    // C mapping (m89): col(lane&15)=batch, row=(lane>>4)*4+reg
    const float gsum = gpart[0][bo] + gpart[1][bo] + gpart[2][bo] + gpart[3][bo];
    const int ci = ro & 3, cl = ((ro >> 2) << 4) + bo;
    const float pre0 = cpart[0][ci][cl] + cpart[1][ci][cl] +
                       cpart[2][ci][cl] + cpart[3][ci][cl];
    const float sg   = 1.f / (1.f + expf(-(gsum + wsb)));
    const float pre  = pre0 + wxb_r;
    const float htld = tanhf(pre);
    const float hp   = myh;
    const float h    = (1.f - sg)*hp + sg*htld;
    // save step-t values for deferred store at step t+1
    myh = h; p_sg = sg; p_htld = htld; p_hp = hp;
    {
      const unsigned hb = (unsigned)f2bf(h);
      unsigned short* hptr = hbuf + ((size_t)(t & 1)*NB + b_glob)*NH + rg;
      asm volatile("global_store_short %0, %1, off sc0 sc1"
                   :: "v"(hptr), "v"(hb) : "memory");
    }
    asm volatile("s_waitcnt vmcnt(0)" ::: "memory");
    __syncthreads();                   // barrier (b): all h stores at LLC
    if (tid == 0) {
      unsigned int one = 1u;
      unsigned int* fp = flags + ((size_t)bg*NT + t)*64 + sl;
      asm volatile("global_store_dword %0, %1, off sc0 sc1"
                   :: "v"(fp), "v"(one) : "memory");
    }
  }

  // ---- final step's deferred outputs ----
  {
    const size_t obase = ((size_t)b_glob*NT + (NT-1))*NH + rg;
    const float sp  = p_sg * (1.f - p_sg);
    const float rdv = (p_htld - p_hp)*(sp*usr_r) +
                      p_sg*(1.f - p_htld*p_htld)*whd_r;
    __builtin_nontemporal_store(myh, &hs_o[obase]);
    __builtin_nontemporal_store(p_sg, &g_o[obase]);
    __builtin_nontemporal_store(1.f - p_sg, &l_o[obase]);
    __builtin_nontemporal_store(rdv, &rd_o[obase]);
  }
}

// ys[b,t] = out_w . hs[b,t,:] + out_b
__global__ void yfinish_kernel(const float* __restrict__ hs,
                               const float* __restrict__ out_w,
                               const float* __restrict__ out_b,
                               float* __restrict__ ys)
{
  const int row  = (int)blockIdx.x*4 + ((int)threadIdx.x >> 6);
  const int lane = (int)threadIdx.x & 63;
  const float4* hp = (const float4*)(hs + (size_t)row*NH);
  const float4* wp = (const float4*)out_w;
  float s = 0.f;
  #pragma unroll
  for (int i = 0; i < 4; ++i) {
    const float4 h4 = hp[i*64 + lane];
    const float4 w4 = wp[i*64 + lane];
    s += h4.x*w4.x + h4.y*w4.y + h4.z*w4.z + h4.w*w4.w;
  }
  #pragma unroll
  for (int off = 32; off > 0; off >>= 1) s += __shfl_xor(s, off, 64);
  if (lane == 0) ys[row] = s + out_b[0];
}

extern "C" void kernel_launch(void* const* d_in, const int* in_sizes, int n_in,
                              void* d_out, int out_size, void* d_ws, size_t ws_size,
                              hipStream_t stream)
{
  (void)in_sizes; (void)n_in; (void)out_size; (void)ws_size;
  const float* x     = (const float*)d_in[0];
  const float* Wx_w  = (const float*)d_in[1];
  const float* Wx_b  = (const float*)d_in[2];
  const float* Wh_w  = (const float*)d_in[3];
  const float* Ws_w  = (const float*)d_in[4];
  const float* Ws_b  = (const float*)d_in[5];
  const float* Us_w  = (const float*)d_in[6];
  const float* out_w = (const float*)d_in[7];
  const float* out_b = (const float*)d_in[8];
  float* out = (float*)d_out;

  char* ws = (char*)d_ws;
  unsigned short* hbuf = (unsigned short*)ws;                 // bf16, 256 KB
  unsigned int* flags  = (unsigned int*)(ws + 262144);        // 4*512*64*4 = 512 KB

  (void)hipMemsetAsync(flags, 0, (size_t)4*NT*64*sizeof(unsigned int), stream);
  rnn_step_kernel<<<dim3(256), dim3(256), 0, stream>>>(
      x, Wx_w, Wx_b, Wh_w, Ws_w, Ws_b, Us_w, out, hbuf, flags);
  yfinish_kernel<<<dim3((NB*NT)/4), dim3(256), 0, stream>>>(
      out + (size_t)NB*NT, out_w, out_b, out);
}